// Round 11
// baseline (319.674 us; speedup 1.0000x reference)
//
#include <hip/hip_runtime.h>
#include <math.h>

#define NN 25600      // total nodes
#define BB 512        // graphs
#define NP 50         // nodes per graph
#define EPG 400       // edges per graph
#define EE 204800     // total edges
#define HH 8
#define FF 512
#define GRUH 128
#define GRUIN 1024

typedef unsigned short ushort_t;
typedef __attribute__((ext_vector_type(8))) short bf16x8;
typedef __attribute__((ext_vector_type(4))) float f32x4;

__device__ __forceinline__ float wave_reduce_sum(float v) {
  #pragma unroll
  for (int m = 32; m >= 1; m >>= 1) v += __shfl_xor(v, m, 64);
  return v;
}

__device__ __forceinline__ ushort_t f2bf(float x) {
  union { float f; unsigned int u; } v; v.f = x;
  unsigned int r = v.u + 0x7fffu + ((v.u >> 16) & 1u);   // RNE
  return (ushort_t)(r >> 16);
}

__device__ __forceinline__ float bf2f(ushort_t u) {
  union { unsigned int u; float f; } v; v.u = ((unsigned int)u) << 16;
  return v.f;
}

__device__ __forceinline__ void gload_lds16(const ushort_t* g, ushort_t* l) {
  __builtin_amdgcn_global_load_lds(
      (const __attribute__((address_space(1))) void*)g,
      (__attribute__((address_space(3))) void*)l, 16, 0, 0);
}

// Merged prologue, 1409 blocks (see R8).
__global__ __launch_bounds__(256) void k_pre(
    const float* __restrict__ W2, const float* __restrict__ W3,
    const float* __restrict__ Wih,
    ushort_t* __restrict__ w2t, ushort_t* __restrict__ w3t, ushort_t* __restrict__ wiht,
    const int* __restrict__ ei, const float* __restrict__ eattr,
    int* __restrict__ rowp, ushort_t* __restrict__ esrc, float* __restrict__ eea,
    float* __restrict__ lattr,
    const float* __restrict__ We1, const float* __restrict__ ae1,
    const float* __restrict__ We2, const float* __restrict__ ae2,
    const float* __restrict__ We3, const float* __restrict__ ae3,
    float* __restrict__ wdot) {
  int b = blockIdx.x, tid = threadIdx.x;
  __shared__ float t[32][33];
  __shared__ int cnt[NP];
  __shared__ float esum[NP];
  __shared__ int rp[NP + 1];
  __shared__ int cur[NP];

  if (b < 896) {
    const float* W; ushort_t* Wt; int K, N, n0, k0;
    if (b < 256)      { W = W2;  Wt = w2t;  K = 512;  N = 512; n0 = (b & 15) * 32;        k0 = (b >> 4) * 32; }
    else if (b < 512) { W = W3;  Wt = w3t;  K = 512;  N = 512; n0 = ((b - 256) & 15) * 32; k0 = ((b - 256) >> 4) * 32; }
    else              { W = Wih; Wt = wiht; K = 1024; N = 384; n0 = ((b - 512) % 12) * 32; k0 = ((b - 512) / 12) * 32; }
    int tx = tid & 31, ty = tid >> 5;
    #pragma unroll
    for (int i = 0; i < 4; i++)
      t[ty + i * 8][tx] = W[(size_t)(k0 + ty + i * 8) * N + n0 + tx];
    __syncthreads();
    #pragma unroll
    for (int i = 0; i < 4; i++)
      Wt[(size_t)(n0 + ty + i * 8) * K + k0 + tx] = f2bf(t[tx][ty + i * 8]);
  } else if (b < 1408) {
    int g = b - 896;
    if (tid < NP) { cnt[tid] = 0; esum[tid] = 0.f; }
    __syncthreads();
    for (int e = tid; e < EPG; e += 256) {
      int ge = g * EPG + e;
      int dl = ei[EE + ge] - g * NP;
      atomicAdd(&cnt[dl], 1);
      atomicAdd(&esum[dl], eattr[ge]);
    }
    __syncthreads();
    if (tid == 0) {
      int s = 0;
      for (int i = 0; i < NP; i++) { rp[i] = s; cur[i] = s; s += cnt[i]; }
      rp[NP] = s;
    }
    __syncthreads();
    if (tid <= NP) rowp[g * 64 + tid] = rp[tid];
    if (tid < NP) lattr[g * NP + tid] = esum[tid] / (float)max(cnt[tid], 1);
    for (int e = tid; e < EPG; e += 256) {
      int ge = g * EPG + e;
      int sl = ei[ge] - g * NP;
      int dl = ei[EE + ge] - g * NP;
      int pos = atomicAdd(&cur[dl], 1);
      esrc[g * EPG + pos] = (ushort_t)sl;
      eea[g * EPG + pos] = eattr[ge];
    }
  } else {
    int w = tid >> 6, lane = tid & 63;
    for (int i = 0; i < 6; i++) {
      int idx = w + 4 * i;
      int l = idx >> 3, h = idx & 7;
      const float* We = l == 0 ? We1 : (l == 1 ? We2 : We3);
      const float* ae = l == 0 ? ae1 : (l == 1 ? ae2 : ae3);
      float v = wave_reduce_sum(We[h * 64 + lane] * ae[h * 64 + lane]);
      if (lane == 0) wdot[l * 8 + h] = v;
    }
  }
}

// Fully-fused GAT layer, 512 threads: block = (graph g, head-half).
// 8 waves: wave w -> head (w&3), feature-half (w>>2)*32.
// K-loop: BK=64, A+B staged via global_load_lds by ALL waves, staging buffers
// ALIASED into hS/Am regions (free after/before use). hS: stride 72 us
// (36 dwords == 4 mod 32 -> banks rotate per row), paired-b32 stores
// (shfl_xor pack, 2 lanes/bank = free). Softmax: waves 0-3, CSR true-max,
// bf16 RMW Am. Out MFMA + bias/relu -> xout or fused pool.
// Input and output buffers must be distinct.
__global__ __launch_bounds__(512, 4) void k_layer(
    const ushort_t* __restrict__ Xbf,
    const float* __restrict__ x4, const float* __restrict__ W1,
    const ushort_t* __restrict__ Wt,
    const float* __restrict__ a_src, const float* __restrict__ a_dst,
    ushort_t* __restrict__ xout, ushort_t* __restrict__ cbf,
    const int* __restrict__ rowp, const ushort_t* __restrict__ esrc,
    const float* __restrict__ eea, const float* __restrict__ lattr,
    const float* __restrict__ wdot_all, const float* __restrict__ bias,
    int layer, int self_loops) {
  int g = blockIdx.x, half = blockIdx.y, tid = threadIdx.x;
  int w = tid >> 6, l = tid & 63;
  int head = w & 3;
  int flb = head * 64 + (w >> 2) * 32;   // wave's local feature base (0..255)
  int fbase = half * 256;
  int m_l = l & 15, quad = l >> 4, rq = quad * 4, kq8 = quad * 8;

  __shared__ __align__(16) ushort_t hS[256 * 72];   // h[fl][s], stride 72; aliased: A-staging [256][64]
  __shared__ __align__(16) ushort_t AmU[12800];     // Am (4 heads x 50 x 64); aliased: B-staging [64][64] / W1s+xs
  __shared__ float pds[512], pdd[512];
  __shared__ float sslS[256], sdlS[256];
  __shared__ ushort_t esrcS[400];
  __shared__ float eeaS[400];
  __shared__ int rowpS[51];
  __shared__ float lattrS[50];

  for (int i = tid; i < 400; i += 512) { esrcS[i] = esrc[g * EPG + i]; eeaS[i] = eea[g * EPG + i]; }
  if (tid <= NP) rowpS[tid] = rowp[g * 64 + tid];
  if (tid < NP) lattrS[tid] = lattr[g * NP + tid];

  f32x4 acc[2][4];
  #pragma unroll
  for (int i = 0; i < 2; i++)
    #pragma unroll
    for (int j = 0; j < 4; j++) acc[i][j] = (f32x4){0.f, 0.f, 0.f, 0.f};

  if (layer == 0) {
    float* W1s = (float*)AmU;            // [4][256]
    float* xs = (float*)AmU + 1024;      // [64][4]
    for (int i = tid; i < 1024; i += 512)
      W1s[i] = W1[(i >> 8) * 512 + fbase + (i & 255)];
    if (tid < NP) *(float4*)(&xs[tid * 4]) = *(const float4*)(&x4[(size_t)(g * NP + tid) * 4]);
    else if (tid < 64) *(float4*)(&xs[tid * 4]) = make_float4(0.f, 0.f, 0.f, 0.f);
    __syncthreads();
    float xr[4][4];
    #pragma unroll
    for (int nt = 0; nt < 4; nt++)
      #pragma unroll
      for (int k = 0; k < 4; k++) xr[nt][k] = xs[(nt * 16 + m_l) * 4 + k];
    #pragma unroll
    for (int mt = 0; mt < 2; mt++) {
      float wv[4][4];
      #pragma unroll
      for (int r = 0; r < 4; r++)
        #pragma unroll
        for (int k = 0; k < 4; k++) wv[r][k] = W1s[k * 256 + flb + mt * 16 + rq + r];
      #pragma unroll
      for (int nt = 0; nt < 4; nt++)
        #pragma unroll
        for (int r = 0; r < 4; r++)
          acc[mt][nt][r] = xr[nt][0] * wv[r][0] + xr[nt][1] * wv[r][1]
                         + xr[nt][2] * wv[r][2] + xr[nt][3] * wv[r][3];
    }
    __syncthreads();   // AmU reused below
  } else {
    // K-loop BK=64: A = Wt rows [fbase..fbase+256) into hS alias, B = 64 node
    // rows into AmU alias. All 8 waves stage; 2 barriers per 64-K.
    ushort_t* hA = hS;    // [256][64] us (32 KB <= 36.9 KB)
    ushort_t* hB = AmU;   // [64][64] us (8 KB <= 25.6 KB)
    int arow = (l >> 3), acol = (l & 7) * 8;
    for (int k0 = 0; k0 < FF; k0 += 64) {
      #pragma unroll
      for (int j = 0; j < 4; j++)
        gload_lds16(Wt + (size_t)(fbase + w * 32 + j * 8 + arow) * FF + k0 + acol,
                    hA + w * 2048 + j * 512);
      gload_lds16(Xbf + (size_t)(g * NP + w * 8 + arow) * FF + k0 + acol,
                  hB + w * 512);
      __syncthreads();
      #pragma unroll
      for (int kc = 0; kc < 2; kc++) {
        bf16x8 bfr[4];
        #pragma unroll
        for (int nt = 0; nt < 4; nt++)
          bfr[nt] = *(const bf16x8*)(hB + (nt * 16 + m_l) * 64 + kc * 32 + kq8);
        #pragma unroll
        for (int mt = 0; mt < 2; mt++) {
          bf16x8 af = *(const bf16x8*)(hA + (flb + mt * 16 + m_l) * 64 + kc * 32 + kq8);
          #pragma unroll
          for (int nt = 0; nt < 4; nt++)
            acc[mt][nt] = __builtin_amdgcn_mfma_f32_16x16x32_bf16(af, bfr[nt], acc[mt][nt], 0, 0, 0);
        }
      }
      __syncthreads();
    }
  }

  // h -> hS (stride 72, paired-b32 stores) + per-wave dot partials.
  // D layout: n=s -> m_l (per nt), m=f -> quad*4+r (per mt)
  float ds[4] = {0.f, 0.f, 0.f, 0.f}, dd[4] = {0.f, 0.f, 0.f, 0.f};
  int rbase = (m_l & 1) * 2;
  #pragma unroll
  for (int mt = 0; mt < 2; mt++) {
    float a_s[4], a_d[4];
    #pragma unroll
    for (int r = 0; r < 4; r++) {
      int fg = fbase + flb + mt * 16 + rq + r;
      a_s[r] = a_src[fg]; a_d[r] = a_dst[fg];
    }
    #pragma unroll
    for (int nt = 0; nt < 4; nt++) {
      unsigned int pk[4];
      #pragma unroll
      for (int r = 0; r < 4; r++) {
        float v = acc[mt][nt][r];
        ds[nt] += v * a_s[r];
        dd[nt] += v * a_d[r];
        float o = __shfl_xor(v, 1, 64);
        unsigned int own = f2bf(v), oth = f2bf(o);
        pk[r] = (m_l & 1) ? (oth | (own << 16)) : (own | (oth << 16));
      }
      int col = nt * 16 + (m_l & ~1);
      int row0 = flb + mt * 16 + rq + rbase;
      *(unsigned int*)(&hS[row0 * 72 + col]) = pk[rbase];
      *(unsigned int*)(&hS[(row0 + 1) * 72 + col]) = pk[rbase + 1];
    }
  }
  #pragma unroll
  for (int nt = 0; nt < 4; nt++) {
    ds[nt] += __shfl_xor(ds[nt], 16, 64); ds[nt] += __shfl_xor(ds[nt], 32, 64);
    dd[nt] += __shfl_xor(dd[nt], 16, 64); dd[nt] += __shfl_xor(dd[nt], 32, 64);
  }
  if (l < 16) {
    #pragma unroll
    for (int nt = 0; nt < 4; nt++) {
      pds[w * 64 + nt * 16 + l] = ds[nt];
      pdd[w * 64 + nt * 16 + l] = dd[nt];
    }
  }
  __syncthreads();

  // zero AmU + combine dot halves
  { uint4* z = (uint4*)AmU; for (int i = tid; i < 1600; i += 512) z[i] = make_uint4(0u, 0u, 0u, 0u); }
  if (tid < 256) {
    sslS[tid] = pds[tid] + pds[tid + 256];
    sdlS[tid] = pdd[tid] + pdd[tid + 256];
  }
  __syncthreads();

  // softmax: waves 0..3, one per head; lanes 0..49 = dst rows
  float wdot = wdot_all[layer * 8 + half * 4 + head];
  if (w < 4 && l < NP) {
    ushort_t* AmH = AmU + w * 3200;
    int d = l;
    int e0 = rowpS[d], e1 = rowpS[d + 1];
    float sd = sdlS[w * 64 + d];
    float m = -1e30f;
    for (int e = e0; e < e1; e++) {
      float al = sslS[w * 64 + esrcS[e]] + sd + eeaS[e] * wdot;
      al = al > 0.f ? al : 0.2f * al;
      m = fmaxf(m, al);
    }
    float al_loop = 0.f;
    if (self_loops) {
      al_loop = sslS[w * 64 + d] + sd + lattrS[d] * wdot;
      al_loop = al_loop > 0.f ? al_loop : 0.2f * al_loop;
      m = fmaxf(m, al_loop);
    }
    if (e1 > e0 || self_loops) {
      float denom = 0.f;
      for (int e = e0; e < e1; e++) {
        float al = sslS[w * 64 + esrcS[e]] + sd + eeaS[e] * wdot;
        al = al > 0.f ? al : 0.2f * al;
        float p = __expf(al - m);
        denom += p;
        int sp = esrcS[e] ^ ((d & 3) << 3);
        float prev = bf2f(AmH[d * 64 + sp]);
        AmH[d * 64 + sp] = f2bf(prev + p);
      }
      if (self_loops) {
        float p = __expf(al_loop - m);
        denom += p;
        int sp = d ^ ((d & 3) << 3);
        float prev = bf2f(AmH[d * 64 + sp]);
        AmH[d * 64 + sp] = f2bf(prev + p);
      }
      float inv = 1.f / (denom + 1e-16f);
      #pragma unroll
      for (int c = 0; c < 8; c++) {
        union { ushort_t u[8]; uint4 q; } pk;
        pk.q = *(uint4*)(AmH + d * 64 + c * 8);
        #pragma unroll
        for (int j = 0; j < 8; j++) pk.u[j] = f2bf(bf2f(pk.u[j]) * inv);
        *(uint4*)(AmH + d * 64 + c * 8) = pk.q;
      }
    }
  }
  __syncthreads();

  // out MFMA: D[m=fl][n=d] = h @ Am^T (k = s); clamp Am row for d>=50
  ushort_t* AmW = AmU + head * 3200;
  f32x4 oacc[2][4];
  #pragma unroll
  for (int i = 0; i < 2; i++)
    #pragma unroll
    for (int j = 0; j < 4; j++) oacc[i][j] = (f32x4){0.f, 0.f, 0.f, 0.f};
  #pragma unroll
  for (int kc = 0; kc < 2; kc++) {
    int kb = kc * 32 + kq8;
    bf16x8 bfr2[4];
    #pragma unroll
    for (int nt = 0; nt < 4; nt++) {
      int d = nt * 16 + m_l;
      int rd = d < NP ? d : 0;
      bfr2[nt] = *(const bf16x8*)(AmW + rd * 64 + (kb ^ ((rd & 3) << 3)));
    }
    #pragma unroll
    for (int mt = 0; mt < 2; mt++) {
      int fl = flb + mt * 16 + m_l;
      bf16x8 afr = *(const bf16x8*)(&hS[fl * 72 + kb]);
      #pragma unroll
      for (int nt = 0; nt < 4; nt++)
        oacc[mt][nt] = __builtin_amdgcn_mfma_f32_16x16x32_bf16(afr, bfr2[nt], oacc[mt][nt], 0, 0, 0);
    }
  }

  // bias + relu
  float vv[2][4][4];
  #pragma unroll
  for (int mt = 0; mt < 2; mt++) {
    const float4 bv = *(const float4*)(&bias[fbase + flb + mt * 16 + rq]);
    #pragma unroll
    for (int nt = 0; nt < 4; nt++) {
      vv[mt][nt][0] = fmaxf(oacc[mt][nt][0] + bv.x, 0.f);
      vv[mt][nt][1] = fmaxf(oacc[mt][nt][1] + bv.y, 0.f);
      vv[mt][nt][2] = fmaxf(oacc[mt][nt][2] + bv.z, 0.f);
      vv[mt][nt][3] = fmaxf(oacc[mt][nt][3] + bv.w, 0.f);
    }
  }

  if (cbf == nullptr) {
    #pragma unroll
    for (int nt = 0; nt < 4; nt++) {
      int d = nt * 16 + m_l;
      if (d < NP) {
        #pragma unroll
        for (int mt = 0; mt < 2; mt++) {
          union { ushort_t u[4]; uint2 v; } pk;
          #pragma unroll
          for (int r = 0; r < 4; r++) pk.u[r] = f2bf(vv[mt][nt][r]);
          *(uint2*)(&xout[(size_t)(g * NP + d) * FF + fbase + flb + mt * 16 + rq]) = pk.v;
        }
      }
    }
  } else {
    // fused pool (layer 3): agents d<5 -> combined[:512]; mean -> combined[512:]
    #pragma unroll
    for (int mt = 0; mt < 2; mt++) {
      float msum[4];
      #pragma unroll
      for (int r = 0; r < 4; r++) {
        float t = 0.f;
        #pragma unroll
        for (int nt = 0; nt < 4; nt++) {
          int d = nt * 16 + m_l;
          t += (d < NP) ? vv[mt][nt][r] : 0.f;
        }
        t += __shfl_xor(t, 1, 64); t += __shfl_xor(t, 2, 64);
        t += __shfl_xor(t, 4, 64); t += __shfl_xor(t, 8, 64);
        msum[r] = t * (1.f / NP);
      }
      if (m_l == 0) {
        union { ushort_t u[4]; uint2 v; } pk;
        #pragma unroll
        for (int r = 0; r < 4; r++) pk.u[r] = f2bf(msum[r]);
        #pragma unroll
        for (int t5 = 0; t5 < 5; t5++)
          *(uint2*)(&cbf[(size_t)(g * 5 + t5) * GRUIN + 512 + fbase + flb + mt * 16 + rq]) = pk.v;
      }
      if (m_l < 5) {   // agents: d = m_l (nt = 0)
        union { ushort_t u[4]; uint2 v; } pk;
        #pragma unroll
        for (int r = 0; r < 4; r++) pk.u[r] = f2bf(vv[mt][0][r]);
        *(uint2*)(&cbf[(size_t)(g * 5 + m_l) * GRUIN + fbase + flb + mt * 16 + rq]) = pk.v;
      }
    }
  }
}

// generic bf16 MFMA GEMM (row-major C fp32) — GRU input GEMM
__global__ __launch_bounds__(256) void k_bgemm(
    const ushort_t* __restrict__ A, const ushort_t* __restrict__ Bt,
    const float* __restrict__ bias, float* __restrict__ C,
    int M, int N, int K) {
  __shared__ ushort_t As[128 * 32];
  __shared__ ushort_t Bs[128 * 32];
  int tid = threadIdx.x;
  int w = tid >> 6, l = tid & 63;
  int row0 = blockIdx.y * 128, col0 = blockIdx.x * 128;
  int wr = w >> 1, wc = w & 1;

  f32x4 acc[4][4];
  #pragma unroll
  for (int i = 0; i < 4; i++)
    #pragma unroll
    for (int j = 0; j < 4; j++) acc[i][j] = (f32x4){0.f, 0.f, 0.f, 0.f};

  int srow = w * 32 + (l >> 2);
  int skcol = (l & 3) * 8;
  const ushort_t* Ag = A + (size_t)(row0 + srow) * K + skcol;
  const ushort_t* Bg = Bt + (size_t)(col0 + srow) * K + skcol;
  ushort_t* AsW = &As[w * 1024];
  ushort_t* BsW = &Bs[w * 1024];

  int m_l = l & 15, kq = (l >> 4) * 8;
  const ushort_t* ArdA = &As[(wr * 64 + m_l) * 32 + kq];
  const ushort_t* BrdB = &Bs[(wc * 64 + m_l) * 32 + kq];

  for (int k0 = 0; k0 < K; k0 += 32) {
    gload_lds16(Ag + k0, AsW);
    gload_lds16(Ag + (size_t)16 * K + k0, AsW + 512);
    gload_lds16(Bg + k0, BsW);
    gload_lds16(Bg + (size_t)16 * K + k0, BsW + 512);
    __syncthreads();
    bf16x8 af[4], bfr[4];
    #pragma unroll
    for (int t = 0; t < 4; t++) {
      af[t]  = *(const bf16x8*)(ArdA + t * 16 * 32);
      bfr[t] = *(const bf16x8*)(BrdB + t * 16 * 32);
    }
    #pragma unroll
    for (int mt = 0; mt < 4; mt++)
      #pragma unroll
      for (int nt = 0; nt < 4; nt++)
        acc[mt][nt] = __builtin_amdgcn_mfma_f32_16x16x32_bf16(af[mt], bfr[nt], acc[mt][nt], 0, 0, 0);
    __syncthreads();
  }

  int cl = l & 15, rq = (l >> 4) * 4;
  #pragma unroll
  for (int mt = 0; mt < 4; mt++) {
    #pragma unroll
    for (int nt = 0; nt < 4; nt++) {
      int col = col0 + wc * 64 + nt * 16 + cl;
      float bv = bias ? bias[col] : 0.f;
      #pragma unroll
      for (int r = 0; r < 4; r++) {
        int row = row0 + wr * 64 + mt * 16 + rq + r;
        C[(size_t)row * N + col] = acc[mt][nt][r] + bv;
      }
    }
  }
}

// GRU (5 steps) + fc1(relu) + fc2 + action_std, one block per batch element
__global__ void k_grufc(const float* __restrict__ gi_all, const float* __restrict__ h0,
                        const float* __restrict__ Whh, const float* __restrict__ bhh,
                        const float* __restrict__ fc1W, const float* __restrict__ fc1b,
                        const float* __restrict__ fc2W, const float* __restrict__ fc2b,
                        const float* __restrict__ log_std, float* __restrict__ dout) {
  int b = blockIdx.x, tid = threadIdx.x;   // 384 threads
  __shared__ float hl[GRUH];
  __shared__ float ghb[384];
  __shared__ float go[5 * GRUH];
  __shared__ float f1[5 * 64];
  if (tid < GRUH) hl[tid] = h0[b * GRUH + tid];
  for (int t = 0; t < 5; t++) {
    __syncthreads();
    float acc = bhh[tid];
    for (int k = 0; k < GRUH; k++) acc += hl[k] * Whh[k * 384 + tid];
    ghb[tid] = acc;
    __syncthreads();
    if (tid < GRUH) {
      const float* gi = gi_all + (size_t)(b * 5 + t) * 384;
      float r = 1.f / (1.f + expf(-(gi[tid] + ghb[tid])));
      float z = 1.f / (1.f + expf(-(gi[128 + tid] + ghb[128 + tid])));
      float nn = tanhf(gi[256 + tid] + r * ghb[256 + tid]);
      float hn = (1.f - z) * nn + z * hl[tid];
      go[t * GRUH + tid] = hn;
      hl[tid] = hn;
    }
  }
  __syncthreads();
  if (tid < GRUH) dout[15360 + b * GRUH + tid] = hl[tid];
  if (tid < 320) {
    int t = tid >> 6, j = tid & 63;
    float acc = fc1b[j];
    for (int k = 0; k < GRUH; k++) acc += go[t * GRUH + k] * fc1W[k * 64 + j];
    f1[t * 64 + j] = fmaxf(acc, 0.f);
  }
  __syncthreads();
  if (tid < 15) {
    int t = tid / 3, o = tid % 3;
    float v = fc2b[o];
    for (int j = 0; j < 64; j++) v += f1[t * 64 + j] * fc2W[j * 3 + o];
    dout[(b * 5 + t) * 3 + o] = v;
    float ls = log_std[o];
    ls = fminf(fmaxf(ls, -20.f), 2.f);
    dout[7680 + (b * 5 + t) * 3 + o] = expf(ls);
  }
}

extern "C" void kernel_launch(void* const* d_in, const int* in_sizes, int n_in,
                              void* d_out, int out_size, void* d_ws, size_t ws_size,
                              hipStream_t stream) {
  const float* x      = (const float*)d_in[0];
  const int*   ei     = (const int*)d_in[1];
  const float* eattr  = (const float*)d_in[2];
  const float* hstate = (const float*)d_in[3];
  const float* W1  = (const float*)d_in[4];
  const float* as1 = (const float*)d_in[5];
  const float* ad1 = (const float*)d_in[6];
  const float* We1 = (const float*)d_in[7];
  const float* ae1 = (const float*)d_in[8];
  const float* b1  = (const float*)d_in[9];
  const float* W2  = (const float*)d_in[10];
  const float* as2 = (const float*)d_in[11];
  const float* ad2 = (const float*)d_in[12];
  const float* We2 = (const float*)d_in[13];
  const float* ae2 = (const float*)d_in[14];
  const float* b2  = (const float*)d_in[15];
  const float* W3  = (const float*)d_in[16];
  const float* as3 = (const float*)d_in[17];
  const float* ad3 = (const float*)d_in[18];
  const float* We3 = (const float*)d_in[19];
  const float* ae3 = (const float*)d_in[20];
  const float* b3  = (const float*)d_in[21];
  const float* Wih = (const float*)d_in[22];
  const float* Whh = (const float*)d_in[23];
  const float* bih = (const float*)d_in[24];
  const float* bhh = (const float*)d_in[25];
  const float* fc1W = (const float*)d_in[26];
  const float* fc1b = (const float*)d_in[27];
  const float* fc2W = (const float*)d_in[28];
  const float* fc2b = (const float*)d_in[29];
  const float* lstd = (const float*)d_in[30];

  float* ws = (float*)d_ws;
  ushort_t* xbf1 = (ushort_t*)ws;                  // (NN+64)*FF us
  ushort_t* xbf2 = (ushort_t*)(ws + 6569984);      // ping-pong
  float* p = ws + 2 * 6569984;
  int*   rowp  = (int*)p;         p += 32768;
  ushort_t* esrc = (ushort_t*)p;  p += 102400;
  float* eea   = p;               p += 204800;
  float* lattr = p;               p += 25600;
  float* wdot  = p;               p += 32;
  ushort_t* w2t  = (ushort_t*)p;  p += 131072;
  ushort_t* w3t  = (ushort_t*)p;  p += 131072;
  ushort_t* wiht = (ushort_t*)p;  p += 196608;
  ushort_t* cbf  = (ushort_t*)p;  p += 1310720;
  float* gi_all  = p;             p += 983040;
  float* dout = (float*)d_out;

  k_pre<<<1409, 256, 0, stream>>>(W2, W3, Wih, w2t, w3t, wiht, ei, eattr,
                                  rowp, esrc, eea, lattr,
                                  We1, ae1, We2, ae2, We3, ae3, wdot);

  k_layer<<<dim3(BB, 2), 512, 0, stream>>>(nullptr, x, W1, nullptr, as1, ad1,
                                           xbf1, nullptr, rowp, esrc, eea, lattr,
                                           wdot, b1, 0, 0);
  k_layer<<<dim3(BB, 2), 512, 0, stream>>>(xbf1, nullptr, nullptr, w2t, as2, ad2,
                                           xbf2, nullptr, rowp, esrc, eea, lattr,
                                           wdot, b2, 1, 1);
  k_layer<<<dim3(BB, 2), 512, 0, stream>>>(xbf2, nullptr, nullptr, w3t, as3, ad3,
                                           nullptr, cbf, rowp, esrc, eea, lattr,
                                           wdot, b3, 2, 1);

  k_bgemm<<<dim3(3, 20), 256, 0, stream>>>(cbf, wiht, bih, gi_all, 2560, 384, GRUIN);

  k_grufc<<<BB, 384, 0, stream>>>(gi_all, hstate, Whh, bhh, fc1W, fc1b,
                                  fc2W, fc2b, lstd, dout);
}

// Round 12
// 293.436 us; speedup vs baseline: 1.0894x; 1.0894x over previous
//
#include <hip/hip_runtime.h>
#include <math.h>

#define NN 25600      // total nodes
#define BB 512        // graphs
#define NP 50         // nodes per graph
#define EPG 400       // edges per graph
#define EE 204800     // total edges
#define HH 8
#define FF 512
#define GRUH 128
#define GRUIN 1024

typedef unsigned short ushort_t;
typedef __attribute__((ext_vector_type(8))) short bf16x8;
typedef __attribute__((ext_vector_type(4))) float f32x4;

__device__ __forceinline__ float wave_reduce_sum(float v) {
  #pragma unroll
  for (int m = 32; m >= 1; m >>= 1) v += __shfl_xor(v, m, 64);
  return v;
}

__device__ __forceinline__ ushort_t f2bf(float x) {
  union { float f; unsigned int u; } v; v.f = x;
  unsigned int r = v.u + 0x7fffu + ((v.u >> 16) & 1u);   // RNE
  return (ushort_t)(r >> 16);
}

__device__ __forceinline__ float bf2f(ushort_t u) {
  union { unsigned int u; float f; } v; v.u = ((unsigned int)u) << 16;
  return v.f;
}

__device__ __forceinline__ void gload_lds16(const ushort_t* g, ushort_t* l) {
  __builtin_amdgcn_global_load_lds(
      (const __attribute__((address_space(1))) void*)g,
      (__attribute__((address_space(3))) void*)l, 16, 0, 0);
}

// Merged prologue, 1409 blocks (see R8).
__global__ __launch_bounds__(256) void k_pre(
    const float* __restrict__ W2, const float* __restrict__ W3,
    const float* __restrict__ Wih,
    ushort_t* __restrict__ w2t, ushort_t* __restrict__ w3t, ushort_t* __restrict__ wiht,
    const int* __restrict__ ei, const float* __restrict__ eattr,
    int* __restrict__ rowp, ushort_t* __restrict__ esrc, float* __restrict__ eea,
    float* __restrict__ lattr,
    const float* __restrict__ We1, const float* __restrict__ ae1,
    const float* __restrict__ We2, const float* __restrict__ ae2,
    const float* __restrict__ We3, const float* __restrict__ ae3,
    float* __restrict__ wdot) {
  int b = blockIdx.x, tid = threadIdx.x;
  __shared__ float t[32][33];
  __shared__ int cnt[NP];
  __shared__ float esum[NP];
  __shared__ int rp[NP + 1];
  __shared__ int cur[NP];

  if (b < 896) {
    const float* W; ushort_t* Wt; int K, N, n0, k0;
    if (b < 256)      { W = W2;  Wt = w2t;  K = 512;  N = 512; n0 = (b & 15) * 32;        k0 = (b >> 4) * 32; }
    else if (b < 512) { W = W3;  Wt = w3t;  K = 512;  N = 512; n0 = ((b - 256) & 15) * 32; k0 = ((b - 256) >> 4) * 32; }
    else              { W = Wih; Wt = wiht; K = 1024; N = 384; n0 = ((b - 512) % 12) * 32; k0 = ((b - 512) / 12) * 32; }
    int tx = tid & 31, ty = tid >> 5;
    #pragma unroll
    for (int i = 0; i < 4; i++)
      t[ty + i * 8][tx] = W[(size_t)(k0 + ty + i * 8) * N + n0 + tx];
    __syncthreads();
    #pragma unroll
    for (int i = 0; i < 4; i++)
      Wt[(size_t)(n0 + ty + i * 8) * K + k0 + tx] = f2bf(t[tx][ty + i * 8]);
  } else if (b < 1408) {
    int g = b - 896;
    if (tid < NP) { cnt[tid] = 0; esum[tid] = 0.f; }
    __syncthreads();
    for (int e = tid; e < EPG; e += 256) {
      int ge = g * EPG + e;
      int dl = ei[EE + ge] - g * NP;
      atomicAdd(&cnt[dl], 1);
      atomicAdd(&esum[dl], eattr[ge]);
    }
    __syncthreads();
    if (tid == 0) {
      int s = 0;
      for (int i = 0; i < NP; i++) { rp[i] = s; cur[i] = s; s += cnt[i]; }
      rp[NP] = s;
    }
    __syncthreads();
    if (tid <= NP) rowp[g * 64 + tid] = rp[tid];
    if (tid < NP) lattr[g * NP + tid] = esum[tid] / (float)max(cnt[tid], 1);
    for (int e = tid; e < EPG; e += 256) {
      int ge = g * EPG + e;
      int sl = ei[ge] - g * NP;
      int dl = ei[EE + ge] - g * NP;
      int pos = atomicAdd(&cur[dl], 1);
      esrc[g * EPG + pos] = (ushort_t)sl;
      eea[g * EPG + pos] = eattr[ge];
    }
  } else {
    int w = tid >> 6, lane = tid & 63;
    for (int i = 0; i < 6; i++) {
      int idx = w + 4 * i;
      int l = idx >> 3, h = idx & 7;
      const float* We = l == 0 ? We1 : (l == 1 ? We2 : We3);
      const float* ae = l == 0 ? ae1 : (l == 1 ? ae2 : ae3);
      float v = wave_reduce_sum(We[h * 64 + lane] * ae[h * 64 + lane]);
      if (lane == 0) wdot[l * 8 + h] = v;
    }
  }
}

// Fully-fused GAT layer, 256 threads: block = (graph g, QUARTER = 2 heads,
// 128 features). 4 waves: wave w -> head (w>>1), feature sub-half (w&1)*32
// -> local features fl in [w*32, w*32+32). LDS ~35 KB -> 4 blocks/CU
// (latency hiding via co-resident blocks, the R9->R12 occupancy play).
// Staging aliased: A (8 KB) into hS (16 KB), B (4 KB) into Am (12.8 KB).
// Softmax: waves 0,1 (one per head), CSR true-max, bf16 RMW Am (R9 machinery).
// Input and output buffers must be distinct.
__global__ __launch_bounds__(256, 4) void k_layer(
    const ushort_t* __restrict__ Xbf,
    const float* __restrict__ x4, const float* __restrict__ W1,
    const ushort_t* __restrict__ Wt,
    const float* __restrict__ a_src, const float* __restrict__ a_dst,
    ushort_t* __restrict__ xout, ushort_t* __restrict__ cbf,
    const int* __restrict__ rowp, const ushort_t* __restrict__ esrc,
    const float* __restrict__ eea, const float* __restrict__ lattr,
    const float* __restrict__ wdot_all, const float* __restrict__ bias,
    int layer, int self_loops) {
  int g = blockIdx.x, q = blockIdx.y, tid = threadIdx.x;
  int w = tid >> 6, l = tid & 63;
  int fbase = q * 128;                 // global feature base of this quarter
  int head_local = w >> 1;             // 0,1
  int m_l = l & 15, quad = l >> 4, rq = quad * 4, kq8 = quad * 8;

  __shared__ __align__(16) ushort_t hS[128 * 64];   // h[fl][s^((fl&3)<<3)]; alias: A-stage [128][32]
  __shared__ __align__(16) ushort_t AmU[6400];      // Am 2 heads x 50 x 64; alias: B-stage [64][32] / W1s+xs
  __shared__ float pds[4 * 64], pdd[4 * 64];
  __shared__ float sslS[128], sdlS[128];
  __shared__ ushort_t esrcS[400];
  __shared__ float eeaS[400];
  __shared__ int rowpS[51];
  __shared__ float lattrS[50];

  for (int i = tid; i < 400; i += 256) { esrcS[i] = esrc[g * EPG + i]; eeaS[i] = eea[g * EPG + i]; }
  if (tid <= NP) rowpS[tid] = rowp[g * 64 + tid];
  if (tid < NP) lattrS[tid] = lattr[g * NP + tid];

  f32x4 acc[2][4];
  #pragma unroll
  for (int i = 0; i < 2; i++)
    #pragma unroll
    for (int j = 0; j < 4; j++) acc[i][j] = (f32x4){0.f, 0.f, 0.f, 0.f};

  if (layer == 0) {
    float* W1s = (float*)AmU;            // [4][128]
    float* xs = (float*)AmU + 512;       // [64][4]
    for (int i = tid; i < 512; i += 256)
      W1s[i] = W1[(i >> 7) * 512 + fbase + (i & 127)];
    if (tid < NP) *(float4*)(&xs[tid * 4]) = *(const float4*)(&x4[(size_t)(g * NP + tid) * 4]);
    else if (tid < 64) *(float4*)(&xs[tid * 4]) = make_float4(0.f, 0.f, 0.f, 0.f);
    __syncthreads();
    float xr[4][4];
    #pragma unroll
    for (int nt = 0; nt < 4; nt++)
      #pragma unroll
      for (int k = 0; k < 4; k++) xr[nt][k] = xs[(nt * 16 + m_l) * 4 + k];
    #pragma unroll
    for (int mt = 0; mt < 2; mt++) {
      float wv[4][4];
      #pragma unroll
      for (int r = 0; r < 4; r++)
        #pragma unroll
        for (int k = 0; k < 4; k++) wv[r][k] = W1s[k * 128 + w * 32 + mt * 16 + rq + r];
      #pragma unroll
      for (int nt = 0; nt < 4; nt++)
        #pragma unroll
        for (int r = 0; r < 4; r++)
          acc[mt][nt][r] = xr[nt][0] * wv[r][0] + xr[nt][1] * wv[r][1]
                         + xr[nt][2] * wv[r][2] + xr[nt][3] * wv[r][3];
    }
    __syncthreads();   // AmU reused below
  } else {
    // K-loop BK=32: A = Wt rows [fbase..fbase+128) -> hS alias (8 KB),
    // B = 64 node rows -> AmU alias (4 KB). All 4 waves stage.
    ushort_t* As = hS;    // [128][32]
    ushort_t* Bs = AmU;   // [64][32]
    const ushort_t* AgBase = Wt + (size_t)(fbase + w * 32 + (l >> 2)) * FF + (l & 3) * 8;
    const ushort_t* Bg = Xbf + (size_t)(g * NP + w * 16 + (l >> 2)) * FF + (l & 3) * 8;
    ushort_t* AsW = As + w * 1024;
    ushort_t* BsW = Bs + w * 512;
    for (int k0 = 0; k0 < FF; k0 += 32) {
      gload_lds16(AgBase + k0, AsW);
      gload_lds16(AgBase + (size_t)16 * FF + k0, AsW + 512);
      gload_lds16(Bg + k0, BsW);
      __syncthreads();
      bf16x8 bfr[4];
      #pragma unroll
      for (int nt = 0; nt < 4; nt++)
        bfr[nt] = *(const bf16x8*)(Bs + (nt * 16 + m_l) * 32 + kq8);
      #pragma unroll
      for (int mt = 0; mt < 2; mt++) {
        bf16x8 af = *(const bf16x8*)(As + (w * 32 + mt * 16 + m_l) * 32 + kq8);
        #pragma unroll
        for (int nt = 0; nt < 4; nt++)
          acc[mt][nt] = __builtin_amdgcn_mfma_f32_16x16x32_bf16(af, bfr[nt], acc[mt][nt], 0, 0, 0);
      }
      __syncthreads();
    }
  }

  // h -> hS (bf16, R9 swizzle) + per-wave dot partials.
  // D layout: n=s -> m_l (per nt), m=f -> quad*4+r (per mt)
  float ds[4] = {0.f, 0.f, 0.f, 0.f}, dd[4] = {0.f, 0.f, 0.f, 0.f};
  #pragma unroll
  for (int mt = 0; mt < 2; mt++) {
    float a_s[4], a_d[4];
    #pragma unroll
    for (int r = 0; r < 4; r++) {
      int fg = fbase + w * 32 + mt * 16 + rq + r;
      a_s[r] = a_src[fg]; a_d[r] = a_dst[fg];
    }
    #pragma unroll
    for (int nt = 0; nt < 4; nt++) {
      int s = nt * 16 + m_l;
      #pragma unroll
      for (int r = 0; r < 4; r++) {
        float v = acc[mt][nt][r];
        ds[nt] += v * a_s[r];
        dd[nt] += v * a_d[r];
        int fl = w * 32 + mt * 16 + rq + r;
        hS[fl * 64 + (s ^ ((fl & 3) << 3))] = f2bf(v);
      }
    }
  }
  #pragma unroll
  for (int nt = 0; nt < 4; nt++) {
    ds[nt] += __shfl_xor(ds[nt], 16, 64); ds[nt] += __shfl_xor(ds[nt], 32, 64);
    dd[nt] += __shfl_xor(dd[nt], 16, 64); dd[nt] += __shfl_xor(dd[nt], 32, 64);
  }
  if (l < 16) {
    #pragma unroll
    for (int nt = 0; nt < 4; nt++) {
      pds[w * 64 + nt * 16 + l] = ds[nt];
      pdd[w * 64 + nt * 16 + l] = dd[nt];
    }
  }
  __syncthreads();

  // zero AmU (12800 B = 800 uint4) + combine per-head dot halves
  { uint4* z = (uint4*)AmU; for (int i = tid; i < 800; i += 256) z[i] = make_uint4(0u, 0u, 0u, 0u); }
  if (tid < 128) {
    int base = (tid >> 6) * 128 + (tid & 63);
    sslS[tid] = pds[base] + pds[base + 64];
    sdlS[tid] = pdd[base] + pdd[base + 64];
  }
  __syncthreads();

  // softmax: waves 0,1 -> head w; lanes 0..49 = dst rows
  if (w < 2 && l < NP) {
    float wdot = wdot_all[layer * 8 + q * 2 + w];
    ushort_t* AmH = AmU + w * 3200;
    int d = l;
    int e0 = rowpS[d], e1 = rowpS[d + 1];
    float sd = sdlS[w * 64 + d];
    float m = -1e30f;
    for (int e = e0; e < e1; e++) {
      float al = sslS[w * 64 + esrcS[e]] + sd + eeaS[e] * wdot;
      al = al > 0.f ? al : 0.2f * al;
      m = fmaxf(m, al);
    }
    float al_loop = 0.f;
    if (self_loops) {
      al_loop = sslS[w * 64 + d] + sd + lattrS[d] * wdot;
      al_loop = al_loop > 0.f ? al_loop : 0.2f * al_loop;
      m = fmaxf(m, al_loop);
    }
    if (e1 > e0 || self_loops) {
      float denom = 0.f;
      for (int e = e0; e < e1; e++) {
        float al = sslS[w * 64 + esrcS[e]] + sd + eeaS[e] * wdot;
        al = al > 0.f ? al : 0.2f * al;
        float p = __expf(al - m);
        denom += p;
        int sp = esrcS[e] ^ ((d & 3) << 3);
        float prev = bf2f(AmH[d * 64 + sp]);
        AmH[d * 64 + sp] = f2bf(prev + p);
      }
      if (self_loops) {
        float p = __expf(al_loop - m);
        denom += p;
        int sp = d ^ ((d & 3) << 3);
        float prev = bf2f(AmH[d * 64 + sp]);
        AmH[d * 64 + sp] = f2bf(prev + p);
      }
      float inv = 1.f / (denom + 1e-16f);
      #pragma unroll
      for (int c = 0; c < 8; c++) {
        union { ushort_t u[8]; uint4 q2; } pk;
        pk.q2 = *(uint4*)(AmH + d * 64 + c * 8);
        #pragma unroll
        for (int j = 0; j < 8; j++) pk.u[j] = f2bf(bf2f(pk.u[j]) * inv);
        *(uint4*)(AmH + d * 64 + c * 8) = pk.q2;
      }
    }
  }
  __syncthreads();

  // out MFMA: D[m=fl][n=d] = h @ Am^T (k = s); clamp Am row for d>=50
  ushort_t* AmW = AmU + head_local * 3200;
  f32x4 oacc[2][4];
  #pragma unroll
  for (int i = 0; i < 2; i++)
    #pragma unroll
    for (int j = 0; j < 4; j++) oacc[i][j] = (f32x4){0.f, 0.f, 0.f, 0.f};
  #pragma unroll
  for (int kc = 0; kc < 2; kc++) {
    int kb = kc * 32 + kq8;
    bf16x8 bfr2[4];
    #pragma unroll
    for (int nt = 0; nt < 4; nt++) {
      int d = nt * 16 + m_l;
      int rd = d < NP ? d : 0;
      bfr2[nt] = *(const bf16x8*)(AmW + rd * 64 + (kb ^ ((rd & 3) << 3)));
    }
    #pragma unroll
    for (int mt = 0; mt < 2; mt++) {
      int fl = w * 32 + mt * 16 + m_l;
      bf16x8 afr = *(const bf16x8*)(hS + fl * 64 + (kb ^ ((fl & 3) << 3)));
      #pragma unroll
      for (int nt = 0; nt < 4; nt++)
        oacc[mt][nt] = __builtin_amdgcn_mfma_f32_16x16x32_bf16(afr, bfr2[nt], oacc[mt][nt], 0, 0, 0);
    }
  }

  // bias + relu
  float vv[2][4][4];
  #pragma unroll
  for (int mt = 0; mt < 2; mt++) {
    const float4 bv = *(const float4*)(&bias[fbase + w * 32 + mt * 16 + rq]);
    #pragma unroll
    for (int nt = 0; nt < 4; nt++) {
      vv[mt][nt][0] = fmaxf(oacc[mt][nt][0] + bv.x, 0.f);
      vv[mt][nt][1] = fmaxf(oacc[mt][nt][1] + bv.y, 0.f);
      vv[mt][nt][2] = fmaxf(oacc[mt][nt][2] + bv.z, 0.f);
      vv[mt][nt][3] = fmaxf(oacc[mt][nt][3] + bv.w, 0.f);
    }
  }

  if (cbf == nullptr) {
    #pragma unroll
    for (int nt = 0; nt < 4; nt++) {
      int d = nt * 16 + m_l;
      if (d < NP) {
        #pragma unroll
        for (int mt = 0; mt < 2; mt++) {
          union { ushort_t u[4]; uint2 v; } pk;
          #pragma unroll
          for (int r = 0; r < 4; r++) pk.u[r] = f2bf(vv[mt][nt][r]);
          *(uint2*)(&xout[(size_t)(g * NP + d) * FF + fbase + w * 32 + mt * 16 + rq]) = pk.v;
        }
      }
    }
  } else {
    // fused pool (layer 3): agents d<5 -> combined[:512]; mean -> combined[512:]
    #pragma unroll
    for (int mt = 0; mt < 2; mt++) {
      float msum[4];
      #pragma unroll
      for (int r = 0; r < 4; r++) {
        float t = 0.f;
        #pragma unroll
        for (int nt = 0; nt < 4; nt++) {
          int d = nt * 16 + m_l;
          t += (d < NP) ? vv[mt][nt][r] : 0.f;
        }
        t += __shfl_xor(t, 1, 64); t += __shfl_xor(t, 2, 64);
        t += __shfl_xor(t, 4, 64); t += __shfl_xor(t, 8, 64);
        msum[r] = t * (1.f / NP);
      }
      if (m_l == 0) {
        union { ushort_t u[4]; uint2 v; } pk;
        #pragma unroll
        for (int r = 0; r < 4; r++) pk.u[r] = f2bf(msum[r]);
        #pragma unroll
        for (int t5 = 0; t5 < 5; t5++)
          *(uint2*)(&cbf[(size_t)(g * 5 + t5) * GRUIN + 512 + fbase + w * 32 + mt * 16 + rq]) = pk.v;
      }
      if (m_l < 5) {   // agents: d = m_l (nt = 0)
        union { ushort_t u[4]; uint2 v; } pk;
        #pragma unroll
        for (int r = 0; r < 4; r++) pk.u[r] = f2bf(vv[mt][0][r]);
        *(uint2*)(&cbf[(size_t)(g * 5 + m_l) * GRUIN + fbase + w * 32 + mt * 16 + rq]) = pk.v;
      }
    }
  }
}

// generic bf16 MFMA GEMM (row-major C fp32) — GRU input GEMM
__global__ __launch_bounds__(256) void k_bgemm(
    const ushort_t* __restrict__ A, const ushort_t* __restrict__ Bt,
    const float* __restrict__ bias, float* __restrict__ C,
    int M, int N, int K) {
  __shared__ ushort_t As[128 * 32];
  __shared__ ushort_t Bs[128 * 32];
  int tid = threadIdx.x;
  int w = tid >> 6, l = tid & 63;
  int row0 = blockIdx.y * 128, col0 = blockIdx.x * 128;
  int wr = w >> 1, wc = w & 1;

  f32x4 acc[4][4];
  #pragma unroll
  for (int i = 0; i < 4; i++)
    #pragma unroll
    for (int j = 0; j < 4; j++) acc[i][j] = (f32x4){0.f, 0.f, 0.f, 0.f};

  int srow = w * 32 + (l >> 2);
  int skcol = (l & 3) * 8;
  const ushort_t* Ag = A + (size_t)(row0 + srow) * K + skcol;
  const ushort_t* Bg = Bt + (size_t)(col0 + srow) * K + skcol;
  ushort_t* AsW = &As[w * 1024];
  ushort_t* BsW = &Bs[w * 1024];

  int m_l = l & 15, kq = (l >> 4) * 8;
  const ushort_t* ArdA = &As[(wr * 64 + m_l) * 32 + kq];
  const ushort_t* BrdB = &Bs[(wc * 64 + m_l) * 32 + kq];

  for (int k0 = 0; k0 < K; k0 += 32) {
    gload_lds16(Ag + k0, AsW);
    gload_lds16(Ag + (size_t)16 * K + k0, AsW + 512);
    gload_lds16(Bg + k0, BsW);
    gload_lds16(Bg + (size_t)16 * K + k0, BsW + 512);
    __syncthreads();
    bf16x8 af[4], bfr[4];
    #pragma unroll
    for (int t = 0; t < 4; t++) {
      af[t]  = *(const bf16x8*)(ArdA + t * 16 * 32);
      bfr[t] = *(const bf16x8*)(BrdB + t * 16 * 32);
    }
    #pragma unroll
    for (int mt = 0; mt < 4; mt++)
      #pragma unroll
      for (int nt = 0; nt < 4; nt++)
        acc[mt][nt] = __builtin_amdgcn_mfma_f32_16x16x32_bf16(af[mt], bfr[nt], acc[mt][nt], 0, 0, 0);
    __syncthreads();
  }

  int cl = l & 15, rq = (l >> 4) * 4;
  #pragma unroll
  for (int mt = 0; mt < 4; mt++) {
    #pragma unroll
    for (int nt = 0; nt < 4; nt++) {
      int col = col0 + wc * 64 + nt * 16 + cl;
      float bv = bias ? bias[col] : 0.f;
      #pragma unroll
      for (int r = 0; r < 4; r++) {
        int row = row0 + wr * 64 + mt * 16 + rq + r;
        C[(size_t)row * N + col] = acc[mt][nt][r] + bv;
      }
    }
  }
}

// GRU (5 steps) + fc1(relu) + fc2 + action_std, one block per batch element
__global__ void k_grufc(const float* __restrict__ gi_all, const float* __restrict__ h0,
                        const float* __restrict__ Whh, const float* __restrict__ bhh,
                        const float* __restrict__ fc1W, const float* __restrict__ fc1b,
                        const float* __restrict__ fc2W, const float* __restrict__ fc2b,
                        const float* __restrict__ log_std, float* __restrict__ dout) {
  int b = blockIdx.x, tid = threadIdx.x;   // 384 threads
  __shared__ float hl[GRUH];
  __shared__ float ghb[384];
  __shared__ float go[5 * GRUH];
  __shared__ float f1[5 * 64];
  if (tid < GRUH) hl[tid] = h0[b * GRUH + tid];
  for (int t = 0; t < 5; t++) {
    __syncthreads();
    float acc = bhh[tid];
    for (int k = 0; k < GRUH; k++) acc += hl[k] * Whh[k * 384 + tid];
    ghb[tid] = acc;
    __syncthreads();
    if (tid < GRUH) {
      const float* gi = gi_all + (size_t)(b * 5 + t) * 384;
      float r = 1.f / (1.f + expf(-(gi[tid] + ghb[tid])));
      float z = 1.f / (1.f + expf(-(gi[128 + tid] + ghb[128 + tid])));
      float nn = tanhf(gi[256 + tid] + r * ghb[256 + tid]);
      float hn = (1.f - z) * nn + z * hl[tid];
      go[t * GRUH + tid] = hn;
      hl[tid] = hn;
    }
  }
  __syncthreads();
  if (tid < GRUH) dout[15360 + b * GRUH + tid] = hl[tid];
  if (tid < 320) {
    int t = tid >> 6, j = tid & 63;
    float acc = fc1b[j];
    for (int k = 0; k < GRUH; k++) acc += go[t * GRUH + k] * fc1W[k * 64 + j];
    f1[t * 64 + j] = fmaxf(acc, 0.f);
  }
  __syncthreads();
  if (tid < 15) {
    int t = tid / 3, o = tid % 3;
    float v = fc2b[o];
    for (int j = 0; j < 64; j++) v += f1[t * 64 + j] * fc2W[j * 3 + o];
    dout[(b * 5 + t) * 3 + o] = v;
    float ls = log_std[o];
    ls = fminf(fmaxf(ls, -20.f), 2.f);
    dout[7680 + (b * 5 + t) * 3 + o] = expf(ls);
  }
}

extern "C" void kernel_launch(void* const* d_in, const int* in_sizes, int n_in,
                              void* d_out, int out_size, void* d_ws, size_t ws_size,
                              hipStream_t stream) {
  const float* x      = (const float*)d_in[0];
  const int*   ei     = (const int*)d_in[1];
  const float* eattr  = (const float*)d_in[2];
  const float* hstate = (const float*)d_in[3];
  const float* W1  = (const float*)d_in[4];
  const float* as1 = (const float*)d_in[5];
  const float* ad1 = (const float*)d_in[6];
  const float* We1 = (const float*)d_in[7];
  const float* ae1 = (const float*)d_in[8];
  const float* b1  = (const float*)d_in[9];
  const float* W2  = (const float*)d_in[10];
  const float* as2 = (const float*)d_in[11];
  const float* ad2 = (const float*)d_in[12];
  const float* We2 = (const float*)d_in[13];
  const float* ae2 = (const float*)d_in[14];
  const float* b2  = (const float*)d_in[15];
  const float* W3  = (const float*)d_in[16];
  const float* as3 = (const float*)d_in[17];
  const float* ad3 = (const float*)d_in[18];
  const float* We3 = (const float*)d_in[19];
  const float* ae3 = (const float*)d_in[20];
  const float* b3  = (const float*)d_in[21];
  const float* Wih = (const float*)d_in[22];
  const float* Whh = (const float*)d_in[23];
  const float* bih = (const float*)d_in[24];
  const float* bhh = (const float*)d_in[25];
  const float* fc1W = (const float*)d_in[26];
  const float* fc1b = (const float*)d_in[27];
  const float* fc2W = (const float*)d_in[28];
  const float* fc2b = (const float*)d_in[29];
  const float* lstd = (const float*)d_in[30];

  float* ws = (float*)d_ws;
  ushort_t* xbf1 = (ushort_t*)ws;                  // (NN+64)*FF us
  ushort_t* xbf2 = (ushort_t*)(ws + 6569984);      // ping-pong
  float* p = ws + 2 * 6569984;
  int*   rowp  = (int*)p;         p += 32768;
  ushort_t* esrc = (ushort_t*)p;  p += 102400;
  float* eea   = p;               p += 204800;
  float* lattr = p;               p += 25600;
  float* wdot  = p;               p += 32;
  ushort_t* w2t  = (ushort_t*)p;  p += 131072;
  ushort_t* w3t  = (ushort_t*)p;  p += 131072;
  ushort_t* wiht = (ushort_t*)p;  p += 196608;
  ushort_t* cbf  = (ushort_t*)p;  p += 1310720;
  float* gi_all  = p;             p += 983040;
  float* dout = (float*)d_out;

  k_pre<<<1409, 256, 0, stream>>>(W2, W3, Wih, w2t, w3t, wiht, ei, eattr,
                                  rowp, esrc, eea, lattr,
                                  We1, ae1, We2, ae2, We3, ae3, wdot);

  k_layer<<<dim3(BB, 4), 256, 0, stream>>>(nullptr, x, W1, nullptr, as1, ad1,
                                           xbf1, nullptr, rowp, esrc, eea, lattr,
                                           wdot, b1, 0, 0);
  k_layer<<<dim3(BB, 4), 256, 0, stream>>>(xbf1, nullptr, nullptr, w2t, as2, ad2,
                                           xbf2, nullptr, rowp, esrc, eea, lattr,
                                           wdot, b2, 1, 1);
  k_layer<<<dim3(BB, 4), 256, 0, stream>>>(xbf2, nullptr, nullptr, w3t, as3, ad3,
                                           nullptr, cbf, rowp, esrc, eea, lattr,
                                           wdot, b3, 2, 1);

  k_bgemm<<<dim3(3, 20), 256, 0, stream>>>(cbf, wiht, bih, gi_all, 2560, 384, GRUIN);

  k_grufc<<<BB, 384, 0, stream>>>(gi_all, hstate, Whh, bhh, fc1W, fc1b,
                                  fc2W, fc2b, lstd, dout);
}